// Round 8
// baseline (97.848 us; speedup 1.0000x reference)
//
#include <hip/hip_runtime.h>

#define THREADS 256
#define QPT 16             // queries per thread, scalar registers
#define SLICES 64
#define NPTS 8192
#define BATCH 4
#define SLICE (NPTS / SLICES)   // 128 targets per block
#define NMINS (2 * BATCH * NPTS)            // 65536

typedef float f4 __attribute__((ext_vector_type(4)));

// ws layout: [2][BATCH][NPTS] uint (float bits) min arrays = 65536 entries = 256 KB

__global__ void chamfer_init(unsigned int* mins, float* out) {
    int i = blockIdx.x * blockDim.x + threadIdx.x;
    mins[i] = 0x7F800000u;  // +inf
    if (i == 0) out[0] = 0.0f;
}

__global__ __launch_bounds__(THREADS, 4) void chamfer_main(
    const float* __restrict__ p1, const float* __restrict__ p2,
    unsigned int* __restrict__ mins)
{
    const int tid  = threadIdx.x;
    const int bz   = blockIdx.z;         // 0..7 : dir*4 + batch
    const int dir  = bz >> 2;
    const int b    = bz & 3;
    const int qbase = blockIdx.x * (THREADS * QPT);
    const int tbase = blockIdx.y * SLICE;

    const float* __restrict__ qsrc = (dir == 0) ? p1 : p2;
    const float* __restrict__ tsrc = (dir == 0) ? p2 : p1;

    // ---- stage transformed targets into LDS: (-2x, -2y, -2z, |t|^2) ----
    __shared__ f4 tgt[SLICE];
    {
        const float* tp = tsrc + ((size_t)b * NPTS + tbase) * 3;
        for (int k = tid; k < SLICE; k += THREADS) {
            float x = tp[k * 3 + 0];
            float y = tp[k * 3 + 1];
            float z = tp[k * 3 + 2];
            tgt[k] = f4{-2.0f * x, -2.0f * y, -2.0f * z,
                        fmaf(x, x, fmaf(y, y, z * z))};
        }
    }

    // ---- load this thread's queries into scalar registers ----
    // NOTE: deliberately scalar float (no float2/f2): v_pk_fma_f32 measured at
    // ~half the scalar v_fma_f32 FLOP rate on gfx950 (rounds 5-7: dur pinned at
    // 44us == pk-rate model; scalar model predicts ~24us pipe time).
    float qx[QPT], qy[QPT], qz[QPT], best[QPT];
#pragma unroll
    for (int j = 0; j < QPT; ++j) {
        const int q = qbase + j * THREADS + tid;
        const float* pq = qsrc + ((size_t)b * NPTS + q) * 3;
        qx[j] = pq[0];
        qy[j] = pq[1];
        qz[j] = pq[2];
        best[j] = 3.0e38f;
    }

    __syncthreads();

    // ---- main loop: 2 targets/iter, scalar FMA chains + min3 fold ----
    // da = fma(qz,-2z, |t|^2); da = fma(qy,-2y, da); da = fma(qx,-2x, da)
    // best = v_min3_f32(best, da, db)
#pragma unroll 2
    for (int m = 0; m < SLICE; m += 2) {
        f4 ta = tgt[m];
        f4 tb = tgt[m + 1];
#pragma unroll
        for (int j = 0; j < QPT; ++j) {
            float da = fmaf(qz[j], ta.z, ta.w);
            da = fmaf(qy[j], ta.y, da);
            da = fmaf(qx[j], ta.x, da);
            float db = fmaf(qz[j], tb.z, tb.w);
            db = fmaf(qy[j], tb.y, db);
            db = fmaf(qx[j], tb.x, db);
            best[j] = fminf(fminf(best[j], da), db);   // -> v_min3_f32
        }
    }

    // ---- epilogue: + |q|^2, clamp tiny negative from cancellation ----
    unsigned int* mbase = mins + ((size_t)dir * BATCH + b) * NPTS;
#pragma unroll
    for (int j = 0; j < QPT; ++j) {
        float q2 = fmaf(qx[j], qx[j], fmaf(qy[j], qy[j], qz[j] * qz[j]));
        float v = fmaxf(best[j] + q2, 0.0f);
        atomicMin(&mbase[qbase + j * THREADS + tid], __float_as_uint(v));
    }
}

__global__ __launch_bounds__(THREADS) void chamfer_reduce(
    const uint4* __restrict__ mins, float* __restrict__ out)
{
    const int i = blockIdx.x * THREADS + threadIdx.x;   // 64 blocks * 256 = 16384 uint4
    uint4 u = mins[i];
    float s = __uint_as_float(u.x) + __uint_as_float(u.y)
            + __uint_as_float(u.z) + __uint_as_float(u.w);
#pragma unroll
    for (int off = 32; off >= 1; off >>= 1)
        s += __shfl_down(s, off, 64);
    __shared__ float partial[THREADS / 64];
    if ((threadIdx.x & 63) == 0) partial[threadIdx.x >> 6] = s;
    __syncthreads();
    if (threadIdx.x == 0) {
        float tot = 0.0f;
#pragma unroll
        for (int w = 0; w < THREADS / 64; ++w) tot += partial[w];
        atomicAdd(out, tot * (1.0f / (BATCH * NPTS)));
    }
}

extern "C" void kernel_launch(void* const* d_in, const int* in_sizes, int n_in,
                              void* d_out, int out_size, void* d_ws, size_t ws_size,
                              hipStream_t stream) {
    const float* p1 = (const float*)d_in[0];
    const float* p2 = (const float*)d_in[1];
    unsigned int* mins = (unsigned int*)d_ws;   // 65536 uints
    float* out = (float*)d_out;

    // init mins to +inf, out to 0
    chamfer_init<<<NMINS / THREADS, THREADS, 0, stream>>>(mins, out);

    // main: x = query blocks (8192/(256*16)=2), y = target slices (64), z = dir*4+batch
    dim3 grid(NPTS / (THREADS * QPT), SLICES, 2 * BATCH);
    chamfer_main<<<grid, THREADS, 0, stream>>>(p1, p2, mins);

    // parallel reduce: 65536 mins / 4 per thread / 256 per block = 64 blocks
    chamfer_reduce<<<NMINS / (4 * THREADS), THREADS, 0, stream>>>(
        (const uint4*)mins, out);
}